// Round 4
// baseline (248.822 us; speedup 1.0000x reference)
//
#include <hip/hip_runtime.h>
#include <math.h>
#include <string.h>

// ============================================================================
// WaveletBasis as bf16 MFMA GEMM: M=32768(B), N=64(O), K=1024*9.
// K layout: 128 "runs" of 72 k-values, run R = features [8R,8R+8). Within a
// run, feature pair p occupies shorts [18p,18p+18):
//   [basis(f_even) n=0..7 | x_even | x_odd | basis(f_odd) n=0..7]
// Flat K32-step g: chunk c=g/9, octet j=g%9, lane-group q holds run 4c+q.
//
// ROUND 4: occupancy attack. M-tile 32, 1024 blocks, launch_bounds(256,4)
// -> 4 blocks/CU, 16 waves/CU (round 3: 2 blocks, 8 waves, 48% idle from
// phase coupling). Superchunk = 8 runs (18 steps, 36KB single A-buffer).
// K-split 4 ways with per-superchunk rotation (balanced 4.5 steps/wave).
// Bucket j via 7 exact f32 threshold compares (host-computed boundaries of
// the f64-accurate reference pipeline — bit-identical to round 3's
// window+fallback, no transcendentals on device). Epilogue rebuilt on the
// consecutive-lane zero-conflict LDS idiom (round 3 epilogue cost ~15us in
// 16-way bank conflicts).
// ============================================================================

typedef __attribute__((ext_vector_type(8))) short short8;
typedef __attribute__((ext_vector_type(4))) float f32x4;

__device__ __forceinline__ unsigned int f2bf(float f) {
  unsigned int u = __float_as_uint(f);
  u += 0x7FFFu + ((u >> 16) & 1u);   // RNE; finite inputs
  return u >> 16;
}

// 4 dwords = 8 bf16 basis values (n=0..7) as a function of bucket j.
__device__ __forceinline__ void gen_basis(int j, unsigned int* d) {
  d[0] = (j < 4) ? 0x3F803F80u : 0xBF803F80u;                  // [phi=1, psi0=+-1]
  unsigned int sq1 = (j & 2) ? 0xBFB5u : 0x3FB5u;              // +-sqrt2
  d[1] = (j & 4) ? (sq1 << 16) : sq1;                          // one-hot k1=j>>2
  unsigned long long sd2 = (j & 1) ? 0xC000ull : 0x4000ull;    // +-2
  unsigned long long d23 = sd2 << ((j & 6) << 3);              // << 16*(j>>1)
  d[2] = (unsigned int)d23;
  d[3] = (unsigned int)(d23 >> 32);
}

#define BARRIER() __asm__ volatile("s_waitcnt lgkmcnt(0)\n\ts_barrier" ::: "memory")

// ---------------------------------------------------------------------------
// K1: W swizzle into MFMA B-fragment order under the run/pair K layout.
// Wsw[(g*4+t)*64 + l] = octet j=g%9 of run R=(g/9)*4+(l>>4), col o=t*16+(l&15)
// ---------------------------------------------------------------------------
__global__ __launch_bounds__(256) void build_w(const float* __restrict__ coeffs,
                                               const float* __restrict__ bw,
                                               uint4* __restrict__ Wsw) {
  const int l = threadIdx.x & 63;
  const int t = threadIdx.x >> 6;   // 0..3
  const int g = blockIdx.x;         // 0..287
  const int c = g / 9, j = g - c * 9;
  const int R = c * 4 + (l >> 4);
  const int o = t * 16 + (l & 15);
  unsigned int dwv[4];
#pragma unroll
  for (int jj = 0; jj < 8; ++jj) {
    int d = 8 * j + jj;             // run-local short index 0..71
    int p = d / 18;
    int e = d - p * 18;
    int f, n;
    if (e < 8)       { f = 8 * R + 2 * p;     n = e; }
    else if (e == 8) { f = 8 * R + 2 * p;     n = 8; }
    else if (e == 9) { f = 8 * R + 2 * p + 1; n = 8; }
    else             { f = 8 * R + 2 * p + 1; n = e - 10; }
    float v = (n < 8) ? coeffs[(f * 64 + o) * 8 + n] : bw[f * 64 + o];
    unsigned int h = f2bf(v);
    if (jj & 1) dwv[jj >> 1] |= h << 16; else dwv[jj >> 1] = h;
  }
  uint4 qq; qq.x = dwv[0]; qq.y = dwv[1]; qq.z = dwv[2]; qq.w = dwv[3];
  Wsw[(g * 4 + t) * 64 + l] = qq;
}

// ---------------------------------------------------------------------------
// K2: 1024 blocks x 256 thr (4 waves), 4 blocks/CU. Block = 32 rows x 64 cols.
// Superchunk sc = 8 runs (features [64sc,64sc+64)) = 18 K32-steps, 36KB LDS.
// Builder: thread (m=tid&31, r=tid>>5) builds run sc*8+r for row m.
// MFMA: wave w takes steps s in [0,18) with s%4 == (w ^ 2*(sc&1)).
// ---------------------------------------------------------------------------
__global__ __launch_bounds__(256, 4) void wavelet_gemm(const float* __restrict__ x,
                                                       const uint4* __restrict__ Wsw,
                                                       float* __restrict__ out,
                                                       int out_size,
                                                       float4 Ta, float4 Tb) {
  __shared__ uint4 Albuf[18 * 4 * 32];   // 36 KB; reused as partial-C at end
  const int tid = threadIdx.x;
  const int l = tid & 63;
  const int w = tid >> 6;            // wave 0..3
  const int q = l >> 4;
  const int mm = l & 15;
  const int m = tid & 31;            // builder row 0..31
  const int r = tid >> 5;            // builder run-in-superchunk 0..7
  const long rowbase = (long)blockIdx.x * 32;

  f32x4 acc[8];
#pragma unroll
  for (int i = 0; i < 8; ++i) acc[i] = (f32x4){0.f, 0.f, 0.f, 0.f};

  const float* xrow = x + (rowbase + m) * 1024 + r * 8;
  // builder LDS base: octet gg of run r -> step s=(r>>2)*9+gg, lane-group r&3
  const int wboff = ((r >> 2) * 36 + (r & 3)) * 32 + m;

  float4 xa = *(const float4*)(xrow);
  float4 xb = *(const float4*)(xrow + 4);

  for (int sc = 0; sc < 16; ++sc) {
    // ---------------- builder: 8 features (one run) -> 9 uint4 -> LDS -------
    float xv[8];
    xv[0] = xa.x; xv[1] = xa.y; xv[2] = xa.z; xv[3] = xa.w;
    xv[4] = xb.x; xv[5] = xb.y; xv[6] = xb.z; xv[7] = xb.w;
    unsigned int dw[36];
#pragma unroll
    for (int p = 0; p < 4; ++p) {
      float xe = xv[2 * p], xo = xv[2 * p + 1];
      // exact bucket: count of thresholds below x (boundaries of the
      // f64-accurate reference f32 pipeline, computed on host)
      int je = (xe >= Ta.x) + (xe >= Ta.y) + (xe >= Ta.z) + (xe >= Ta.w)
             + (xe >= Tb.x) + (xe >= Tb.y) + (xe >= Tb.z);
      int jo = (xo >= Ta.x) + (xo >= Ta.y) + (xo >= Ta.z) + (xo >= Ta.w)
             + (xo >= Tb.x) + (xo >= Tb.y) + (xo >= Tb.z);
      gen_basis(je, &dw[9 * p]);
      dw[9 * p + 4] = f2bf(xe) | (f2bf(xo) << 16);
      gen_basis(jo, &dw[9 * p + 5]);
    }
#pragma unroll
    for (int gg = 0; gg < 9; ++gg) {
      uint4 qv; qv.x = dw[4 * gg]; qv.y = dw[4 * gg + 1];
      qv.z = dw[4 * gg + 2]; qv.w = dw[4 * gg + 3];
      Albuf[wboff + gg * 128] = qv;
    }
    BARRIER();                              // A visible
    if (sc + 1 < 16) {                      // x prefetch rides over MFMA phase
      xa = *(const float4*)(xrow + (sc + 1) * 64);
      xb = *(const float4*)(xrow + (sc + 1) * 64 + 4);
    }
    // ---------------- MFMA: this wave's steps (rotated split) ---------------
    const int t = w ^ ((sc & 1) << 1);
    const int NS = (t < 2) ? 5 : 4;
    for (int i = 0; i < NS; ++i) {
      const int s = t + 4 * i;
      const uint4* ab = Albuf + (s * 4 + q) * 32 + mm;
      short8 a0 = __builtin_bit_cast(short8, ab[0]);
      short8 a1 = __builtin_bit_cast(short8, ab[16]);
      const uint4* wp = Wsw + (size_t)(sc * 18 + s) * 256 + l;
      short8 b0 = __builtin_bit_cast(short8, wp[0]);
      short8 b1 = __builtin_bit_cast(short8, wp[64]);
      short8 b2 = __builtin_bit_cast(short8, wp[128]);
      short8 b3 = __builtin_bit_cast(short8, wp[192]);
      acc[0] = __builtin_amdgcn_mfma_f32_16x16x32_bf16(a0, b0, acc[0], 0, 0, 0);
      acc[1] = __builtin_amdgcn_mfma_f32_16x16x32_bf16(a0, b1, acc[1], 0, 0, 0);
      acc[2] = __builtin_amdgcn_mfma_f32_16x16x32_bf16(a0, b2, acc[2], 0, 0, 0);
      acc[3] = __builtin_amdgcn_mfma_f32_16x16x32_bf16(a0, b3, acc[3], 0, 0, 0);
      acc[4] = __builtin_amdgcn_mfma_f32_16x16x32_bf16(a1, b0, acc[4], 0, 0, 0);
      acc[5] = __builtin_amdgcn_mfma_f32_16x16x32_bf16(a1, b1, acc[5], 0, 0, 0);
      acc[6] = __builtin_amdgcn_mfma_f32_16x16x32_bf16(a1, b2, acc[6], 0, 0, 0);
      acc[7] = __builtin_amdgcn_mfma_f32_16x16x32_bf16(a1, b3, acc[7], 0, 0, 0);
    }
    BARRIER();                              // LDS reads drained before rewrite
  }

  // ---- K-reduction epilogue, zero-conflict (consecutive-lane) layout ------
  // acc slot s = rt*4+tt: rows 16rt+4q+e, col 16tt+mm.
  float* P = (float*)Albuf;                 // 4 regions x 2048 floats = 32 KB
#pragma unroll
  for (int s = 0; s < 8; ++s)
    *(f32x4*)(P + w * 2048 + s * 256 + 4 * l) = acc[s];
  BARRIER();
  float* og = out + (size_t)rowbase * 64;
#pragma unroll
  for (int si = 0; si < 2; ++si) {
    const int s = 2 * w + si;               // this wave reduces slots 2w,2w+1
    f32x4 v = *(f32x4*)(P + 0 * 2048 + s * 256 + 4 * l);
    v = v + *(f32x4*)(P + 1 * 2048 + s * 256 + 4 * l);
    v = v + *(f32x4*)(P + 2 * 2048 + s * 256 + 4 * l);
    v = v + *(f32x4*)(P + 3 * 2048 + s * 256 + 4 * l);
    const int rt = s >> 2, tt = s & 3;
#pragma unroll
    for (int e = 0; e < 4; ++e)
      og[(16 * rt + 4 * q + e) * 64 + 16 * tt + mm] = v[e];
  }
  if (blockIdx.x == 0 && tid == 0) out[out_size - 1] = 0.0f;  // kl = 0
}

// ---------------------------------------------------------------------------
// Host: exact f32 bucket boundaries of the reference pipeline.
// Xk = smallest f32 x with ((float)tanh((double)x) + 1.0f)*0.5f*8.0f >= k.
// ---------------------------------------------------------------------------
static unsigned int f32key(float f) {
  unsigned int u; memcpy(&u, &f, 4);
  return (u & 0x80000000u) ? ~u : (u | 0x80000000u);
}
static float f32unkey(unsigned int k) {
  unsigned int u = (k & 0x80000000u) ? (k ^ 0x80000000u) : ~k;
  float f; memcpy(&f, &u, 4);
  return f;
}
static bool pipe_ge(float x, int k) {
  float tf = (float)tanh((double)x);
  float s = (tf + 1.0f) * 0.5f;
  float t8 = s * 8.0f;
  return t8 >= (float)k;
}
static void thresholds(float* X) {
  for (int k = 1; k <= 7; ++k) {
    unsigned int lo = f32key(-4.0f);   // P false
    unsigned int hi = f32key(4.0f);    // P true
    while (hi - lo > 1) {
      unsigned int mid = lo + (hi - lo) / 2;
      if (pipe_ge(f32unkey(mid), k)) hi = mid; else lo = mid;
    }
    X[k - 1] = f32unkey(hi);
  }
}

extern "C" void kernel_launch(void* const* d_in, const int* in_sizes, int n_in,
                              void* d_out, int out_size, void* d_ws, size_t ws_size,
                              hipStream_t stream) {
  const float* x      = (const float*)d_in[0];   // [32768,1024] f32
  const float* coeffs = (const float*)d_in[1];   // [1024,64,8] f32
  const float* bw     = (const float*)d_in[2];   // [1024,64] f32
  uint4* Wsw = (uint4*)d_ws;                     // 288*4*64*16 = 1.125 MiB
  float* out = (float*)d_out;

  float X[7];
  thresholds(X);
  float4 Ta; Ta.x = X[0]; Ta.y = X[1]; Ta.z = X[2]; Ta.w = X[3];
  float4 Tb; Tb.x = X[4]; Tb.y = X[5]; Tb.z = X[6]; Tb.w = 1e30f;

  build_w<<<288, 256, 0, stream>>>(coeffs, bw, Wsw);
  wavelet_gemm<<<1024, 256, 0, stream>>>(x, (const uint4*)Wsw, out, out_size, Ta, Tb);
}